// Round 6
// baseline (390.671 us; speedup 1.0000x reference)
//
#include <hip/hip_runtime.h>
#include <hip/hip_bf16.h>
#include <cstdint>

typedef unsigned short u16;
typedef __attribute__((ext_vector_type(8))) short bf16x8;
typedef __attribute__((ext_vector_type(4))) float f32x4;

#define BATCH 4
#define CDIM 256
#define NTOK 4096   // H*W

__device__ inline u16 f2bf(float f) {
  union { float f; uint32_t u; } un; un.f = f;
  uint32_t u = un.u;
  u += 0x7fffu + ((u >> 16) & 1u);
  return (u16)(u >> 16);
}
__device__ inline float bf2f(u16 h) {
  union { uint32_t u; float f; } un; un.u = ((uint32_t)h) << 16; return un.f;
}

__device__ inline void gload_lds16(const u16* g, u16* l) {
  __builtin_amdgcn_global_load_lds((const __attribute__((address_space(1))) void*)g,
                                   (__attribute__((address_space(3))) void*)l, 16, 0, 0);
}

// ---------------------------------------------------------------------------
// LayerNorm: x [B, C, N] -> xn bf16 [B*N, C]
// ---------------------------------------------------------------------------
__global__ __launch_bounds__(256) void ln_kernel(const float* __restrict__ x,
                                                 const float* __restrict__ gamma,
                                                 const float* __restrict__ beta,
                                                 u16* __restrict__ xn) {
  __shared__ float tile[CDIM][33];
  __shared__ float reds[8][32];
  __shared__ float reds2[8][32];
  __shared__ float mu_s[32], rs_s[32];

  int b  = blockIdx.x >> 7;
  int n0 = (blockIdx.x & 127) * 32;
  const float* xb = x + (size_t)b * CDIM * NTOK;

  int t = threadIdx.x & 31;
  int g = threadIdx.x >> 5;

  for (int c = g; c < CDIM; c += 8)
    tile[c][t] = xb[(size_t)c * NTOK + n0 + t];
  __syncthreads();

  float s = 0.f, s2 = 0.f;
  for (int c = g * 32; c < g * 32 + 32; ++c) {
    float v = tile[c][t];
    s += v; s2 += v * v;
  }
  reds[g][t] = s; reds2[g][t] = s2;
  __syncthreads();
  if (threadIdx.x < 32) {
    float ts = 0.f, ts2 = 0.f;
    for (int gg = 0; gg < 8; ++gg) { ts += reds[gg][threadIdx.x]; ts2 += reds2[gg][threadIdx.x]; }
    float mu = ts / CDIM;
    float var = ts2 / CDIM - mu * mu;
    mu_s[threadIdx.x] = mu;
    rs_s[threadIdx.x] = rsqrtf(var + 1e-5f);
  }
  __syncthreads();

  int c = threadIdx.x;
  float gam = gamma[c], bet = beta[c];
  u16* out = xn + ((size_t)b * NTOK + n0) * CDIM;
  for (int tt = 0; tt < 32; ++tt) {
    float v = tile[c][tt];
    float y = (v - mu_s[tt]) * rs_s[tt] * gam + bet;
    out[(size_t)tt * CDIM + c] = f2bf(y);
  }
}

// ---------------------------------------------------------------------------
// W [K, Cout] fp32 -> WT bf16 [Cout, K]
// ---------------------------------------------------------------------------
__global__ __launch_bounds__(256) void wt_kernel(const float* __restrict__ W,
                                                 u16* __restrict__ WT) {
  __shared__ float tile[32][33];
  int i0 = blockIdx.y * 32;
  int j0 = blockIdx.x * 32;
  int tx = threadIdx.x, ty = threadIdx.y;
  for (int r = ty; r < 32; r += 8)
    tile[r][tx] = W[(size_t)(i0 + r) * CDIM + j0 + tx];
  __syncthreads();
  for (int r = ty; r < 32; r += 8)
    WT[(size_t)(j0 + r) * CDIM + i0 + tx] = f2bf(tile[tx][r]);
}

// ---------------------------------------------------------------------------
// bf16 MFMA GEMM (projections): C = A[M,K] * B[Nt,K]^T
// MODE 0: bf16 row-major; MODE 1: bf16 transposed C[n*M+m]
// ---------------------------------------------------------------------------
template <int BM, int BN, int MODE>
__global__ __launch_bounds__(256) void gemm_bt(const u16* __restrict__ Ag,
                                               const u16* __restrict__ Bg,
                                               void* __restrict__ Cg,
                                               int M, int Nt, int K,
                                               size_t sA_, size_t sB_, size_t sC_) {
  constexpr int BK = 32;
  constexpr int TM = BM / 32;
  constexpr int TN = BN / 32;
  __shared__ u16 shA[BM][BK + 8];
  __shared__ u16 shB[BN][BK + 8];

  int bz = blockIdx.z;
  const u16* A = Ag + (size_t)bz * sA_;
  const u16* B = Bg + (size_t)bz * sB_;

  int m0 = blockIdx.y * BM;
  int n0 = blockIdx.x * BN;

  int tid  = threadIdx.x;
  int lane = tid & 63;
  int wave = tid >> 6;
  int wm = wave >> 1, wn = wave & 1;
  int col  = lane & 15;
  int quad = lane >> 4;

  f32x4 acc[TM][TN];
#pragma unroll
  for (int i = 0; i < TM; ++i)
#pragma unroll
    for (int j = 0; j < TN; ++j) acc[i][j] = (f32x4){0.f, 0.f, 0.f, 0.f};

  constexpr int ACH = BM * BK / 8;
  constexpr int BCH = BN * BK / 8;

  for (int kb = 0; kb < K; kb += BK) {
    __syncthreads();
#pragma unroll
    for (int c = tid; c < ACH; c += 256) {
      int row = c >> 2, kc = c & 3;
      *(uint4*)&shA[row][kc * 8] = *(const uint4*)&A[(size_t)(m0 + row) * K + kb + kc * 8];
    }
#pragma unroll
    for (int c = tid; c < BCH; c += 256) {
      int row = c >> 2, kc = c & 3;
      *(uint4*)&shB[row][kc * 8] = *(const uint4*)&B[(size_t)(n0 + row) * K + kb + kc * 8];
    }
    __syncthreads();

    bf16x8 af[TM], bfv[TN];
#pragma unroll
    for (int i = 0; i < TM; ++i)
      af[i] = *(const bf16x8*)&shA[wm * (BM / 2) + i * 16 + col][quad * 8];
#pragma unroll
    for (int j = 0; j < TN; ++j)
      bfv[j] = *(const bf16x8*)&shB[wn * (BN / 2) + j * 16 + col][quad * 8];
#pragma unroll
    for (int i = 0; i < TM; ++i)
#pragma unroll
      for (int j = 0; j < TN; ++j)
        acc[i][j] = __builtin_amdgcn_mfma_f32_16x16x32_bf16(af[i], bfv[j], acc[i][j], 0, 0, 0);
  }

  int r0 = quad * 4;
#pragma unroll
  for (int i = 0; i < TM; ++i) {
    int mbase = m0 + wm * (BM / 2) + i * 16 + r0;
#pragma unroll
    for (int j = 0; j < TN; ++j) {
      int n = n0 + wn * (BN / 2) + j * 16 + col;
#pragma unroll
      for (int r = 0; r < 4; ++r) {
        int m = mbase + r;
        float v = acc[i][j][r];
        if (MODE == 0) {
          ((u16*)Cg)[(size_t)bz * sC_ + (size_t)m * Nt + n] = f2bf(v);
        } else {
          ((u16*)Cg)[(size_t)bz * sC_ + (size_t)n * M + m] = f2bf(v);
        }
      }
    }
  }
}

// ---------------------------------------------------------------------------
// Fused flash attention: wave-owns-rows + cross-tile software pipeline.
// Per iteration t: async prefetch(t+1); S(t) MFMAs; PV(t-1) MFMAs
// (independent chain fills the pipe); stats(t) VALU overlaps drain; ONE
// barrier. KV tile = 32 (128 iters). K x2, V x3, P (per-wave) x2 buffers.
// Staging via global_load_lds (zero VGPR cost). XOR column swizzles:
//   K tile [32][256] u16: pos ^= row ; V tile [256][32] u16: pos ^= (row>>1)&3
// PLD = 40 u16 = 80 B: keeps every b128 P read 16-byte ALIGNED (PLD=36 was
// 72 B -> odd cols 8-byte aligned -> misaligned ds_read_b128 -> MEM_VIOL).
// ---------------------------------------------------------------------------
#define PLD 40

__global__ __launch_bounds__(256, 1) void fa_kernel(const u16* __restrict__ Qg,
                                                    const u16* __restrict__ Kg,
                                                    const u16* __restrict__ Vtg,
                                                    const u16* __restrict__ xng,
                                                    const float* __restrict__ w1p,
                                                    const float* __restrict__ w2p,
                                                    float* __restrict__ outg) {
  // K0 16384 | K1 16384 | V0/V1/V2 3*16384 | P: 4 waves * 2 bufs * 2560 B
  __shared__ __align__(16) char smem[102400];
  u16* Kb0 = (u16*)smem;
  u16* Kb1 = (u16*)(smem + 16384);
  u16* Vb0 = (u16*)(smem + 32768);
  u16* Vb1 = (u16*)(smem + 49152);
  u16* Vb2 = (u16*)(smem + 65536);
  float* otile = (float*)smem;          // epilogue overlay [256][68] f32

  int b  = blockIdx.x & 3;              // XCD swizzle: same XCD -> same batch
  int q0 = (blockIdx.x >> 2) * 64;

  const u16* Q  = Qg  + (size_t)b * NTOK * CDIM;
  const u16* K  = Kg  + (size_t)b * NTOK * CDIM;
  const u16* Vt = Vtg + (size_t)b * NTOK * CDIM;

  int tid  = threadIdx.x;
  int lane = tid & 63;
  int wave = tid >> 6;
  int col = lane & 15, quad = lane >> 4;

  // per-wave P region: 2 buffers of [P1 16x40 | P2 16x40] u16 (2560 B each)
  u16* pw0 = (u16*)(smem + 81920 + wave * 5120);
  u16* pw1 = pw0 + 1280;

  // ---- async stage of one 32-row KV tile ----
  auto stage = [&](int n1, u16* Kdst, u16* Vdst) {
#pragma unroll
    for (int it = 0; it < 4; ++it) {
      int c = it * 256 + wave * 64 + lane;
      int row = c >> 5, pos = c & 31;
      int ch = pos ^ row;
      gload_lds16(K + (size_t)(n1 + row) * CDIM + ch * 8,
                  Kdst + (size_t)(it * 256 + wave * 64) * 8);
    }
#pragma unroll
    for (int it = 0; it < 4; ++it) {
      int c = it * 256 + wave * 64 + lane;
      int row = c >> 2, pos = c & 3;
      int ch = pos ^ ((row >> 1) & 3);
      gload_lds16(Vt + (size_t)row * NTOK + n1 + ch * 8,
                  Vdst + (size_t)(it * 256 + wave * 64) * 8);
    }
  };

  stage(0, Kb0, Vb0);

  // ---- Q A-frags straight from global (16B contiguous per frag) ----
  bf16x8 aq[8];
#pragma unroll
  for (int kk = 0; kk < 8; ++kk)
    aq[kk] = *(const bf16x8*)&Q[(size_t)(q0 + wave * 16 + col) * CDIM + kk * 32 + quad * 8];

  f32x4 o1[16], o2[16];
#pragma unroll
  for (int j = 0; j < 16; ++j) {
    o1[j] = (f32x4){0.f, 0.f, 0.f, 0.f};
    o2[j] = (f32x4){0.f, 0.f, 0.f, 0.f};
  }
  float mr[4], lr[4];
#pragma unroll
  for (int r = 0; r < 4; ++r) { mr[r] = -1e30f; lr[r] = 0.f; }

  // rotating buffer pointers
  u16 *k_cur = Kb0, *k_nxt = Kb1;
  u16 *v_prv = Vb2, *v_cur = Vb0, *v_nxt = Vb1;
  u16 *p_cur = pw0, *p_prv = pw1;

  __syncthreads();   // tile 0 staged (barrier drains vmcnt)

  for (int t = 0; t < 128; ++t) {
    // ---- async prefetch of tile t+1 ----
    if (t < 127)
      stage((t + 1) * 32, k_nxt, v_nxt);

    // ---- S(t) = Q K^T : 16 rows x 32 cols ----
    f32x4 sacc[2];
#pragma unroll
    for (int j = 0; j < 2; ++j) sacc[j] = (f32x4){0.f, 0.f, 0.f, 0.f};
#pragma unroll
    for (int kk = 0; kk < 8; ++kk) {
#pragma unroll
      for (int j = 0; j < 2; ++j) {
        int kr = j * 16 + col;
        bf16x8 bk = *(const bf16x8*)&k_cur[(size_t)kr * 256 + (((kk * 4 + quad) ^ kr) & 31) * 8];
        sacc[j] = __builtin_amdgcn_mfma_f32_16x16x32_bf16(aq[kk], bk, sacc[j], 0, 0, 0);
      }
    }

    // ---- PV(t-1): independent MFMA stream fills the pipe ----
    if (t > 0) {
      bf16x8 pa1 = *(const bf16x8*)&p_prv[(size_t)col * PLD + quad * 8];
      bf16x8 pa2 = *(const bf16x8*)&p_prv[640 + (size_t)col * PLD + quad * 8];
#pragma unroll
      for (int j = 0; j < 16; ++j) {
        int vr = j * 16 + col;
        bf16x8 bv = *(const bf16x8*)&v_prv[(size_t)vr * 32 + ((quad ^ ((vr >> 1) & 3))) * 8];
        o1[j] = __builtin_amdgcn_mfma_f32_16x16x32_bf16(pa1, bv, o1[j], 0, 0, 0);
        o2[j] = __builtin_amdgcn_mfma_f32_16x16x32_bf16(pa2, bv, o2[j], 0, 0, 0);
      }
    }

    // ---- stats(t): register-resident m/l, P1/P2 -> per-wave LDS ----
    float pm[4];
#pragma unroll
    for (int r = 0; r < 4; ++r) pm[r] = fmaxf(sacc[0][r], sacc[1][r]);
#pragma unroll
    for (int off = 1; off < 16; off <<= 1)
#pragma unroll
      for (int r = 0; r < 4; ++r) pm[r] = fmaxf(pm[r], __shfl_xor(pm[r], off));

    float mnew[4], alpha[4], rs[4];
    bool chg = false;
#pragma unroll
    for (int r = 0; r < 4; ++r) {
      mnew[r] = fmaxf(mr[r], pm[r]);
      alpha[r] = __expf(mr[r] - mnew[r]);
      chg = chg || (mnew[r] > mr[r]);
      rs[r] = 0.f;
    }
#pragma unroll
    for (int j = 0; j < 2; ++j)
#pragma unroll
      for (int r = 0; r < 4; ++r) {
        float sv = sacc[j][r];
        float p1 = __expf(sv - mnew[r]);
        rs[r] += p1;
        float p2 = sv > 0.f ? sv * sv : 0.f;
        p_cur[(size_t)(quad * 4 + r) * PLD + j * 16 + col] = f2bf(p1);
        p_cur[640 + (size_t)(quad * 4 + r) * PLD + j * 16 + col] = f2bf(p2);
      }
#pragma unroll
    for (int off = 1; off < 16; off <<= 1)
#pragma unroll
      for (int r = 0; r < 4; ++r) rs[r] += __shfl_xor(rs[r], off);
#pragma unroll
    for (int r = 0; r < 4; ++r) {
      lr[r] = lr[r] * alpha[r] + rs[r];
      mr[r] = mnew[r];
    }

    // ---- rescale O1 only when a row max actually moved (wave-uniform) ----
    if (__any(chg)) {
#pragma unroll
      for (int j = 0; j < 16; ++j)
#pragma unroll
        for (int r = 0; r < 4; ++r) o1[j][r] *= alpha[r];
    }

    __syncthreads();   // prefetch(t+1) landed; all waves done with k_cur

    // rotate buffers
    u16* tk = k_cur; k_cur = k_nxt; k_nxt = tk;
    u16* tv = v_prv; v_prv = v_cur; v_cur = v_nxt; v_nxt = tv;
    u16* tp = p_cur; p_cur = p_prv; p_prv = tp;
  }

  // ---- trailing PV(127) ----
  {
    bf16x8 pa1 = *(const bf16x8*)&p_prv[(size_t)col * PLD + quad * 8];
    bf16x8 pa2 = *(const bf16x8*)&p_prv[640 + (size_t)col * PLD + quad * 8];
#pragma unroll
    for (int j = 0; j < 16; ++j) {
      int vr = j * 16 + col;
      bf16x8 bv = *(const bf16x8*)&v_prv[(size_t)vr * 32 + ((quad ^ ((vr >> 1) & 3))) * 8];
      o1[j] = __builtin_amdgcn_mfma_f32_16x16x32_bf16(pa1, bv, o1[j], 0, 0, 0);
      o2[j] = __builtin_amdgcn_mfma_f32_16x16x32_bf16(pa2, bv, o2[j], 0, 0, 0);
    }
  }

  // ---- epilogue: combine, residual, transpose to [c][n] ----
  float e1 = __expf(w1p[0]), e2 = __expf(w2p[0]);
  float a1 = e1 / (e1 + e2), a2 = e2 / (e1 + e2);
  float linv[4];
#pragma unroll
  for (int r = 0; r < 4; ++r) linv[r] = a1 / lr[r];

  __syncthreads();   // done with K/V/P LDS; reuse as otile

#pragma unroll
  for (int j = 0; j < 16; ++j)
#pragma unroll
    for (int r = 0; r < 4; ++r) {
      int row = wave * 16 + quad * 4 + r;   // local n
      int c   = j * 16 + col;
      float v = o1[j][r] * linv[r] + a2 * o2[j][r];
      v += bf2f(xng[((size_t)b * NTOK + q0 + row) * CDIM + c]);
      otile[(size_t)c * 68 + row] = v;
    }
  __syncthreads();

#pragma unroll
  for (int it = 0; it < 16; ++it) {
    int c  = it * 16 + (tid >> 4);
    int ch = tid & 15;
    *(float4*)&outg[((size_t)b * CDIM + c) * NTOK + q0 + ch * 4] =
        *(const float4*)&otile[(size_t)c * 68 + ch * 4];
  }
}

// ---------------------------------------------------------------------------
extern "C" void kernel_launch(void* const* d_in, const int* in_sizes, int n_in,
                              void* d_out, int out_size, void* d_ws, size_t ws_size,
                              hipStream_t stream) {
  const float* x     = (const float*)d_in[0];
  const float* gamma = (const float*)d_in[1];
  const float* beta  = (const float*)d_in[2];
  const float* Wq    = (const float*)d_in[3];
  const float* Wk    = (const float*)d_in[4];
  const float* Wv    = (const float*)d_in[5];
  const float* w1    = (const float*)d_in[6];
  const float* w2    = (const float*)d_in[7];
  float* out = (float*)d_out;

  char* ws = (char*)d_ws;
  size_t off = 0;
  u16* xn  = (u16*)(ws + off); off += (size_t)BATCH * NTOK * CDIM * 2;
  u16* WqT = (u16*)(ws + off); off += (size_t)CDIM * CDIM * 2;
  u16* WkT = (u16*)(ws + off); off += (size_t)CDIM * CDIM * 2;
  u16* WvT = (u16*)(ws + off); off += (size_t)CDIM * CDIM * 2;
  u16* Qb  = (u16*)(ws + off); off += (size_t)BATCH * NTOK * CDIM * 2;
  u16* Kb  = (u16*)(ws + off); off += (size_t)BATCH * NTOK * CDIM * 2;
  u16* VT  = (u16*)(ws + off); off += (size_t)BATCH * NTOK * CDIM * 2;  // [b][c][n]

  // 1) LayerNorm -> xn bf16 [B*N, C]
  ln_kernel<<<dim3(BATCH * (NTOK / 32)), 256, 0, stream>>>(x, gamma, beta, xn);

  // 2) weight transposes
  wt_kernel<<<dim3(8, 8), dim3(32, 8), 0, stream>>>(Wq, WqT);
  wt_kernel<<<dim3(8, 8), dim3(32, 8), 0, stream>>>(Wk, WkT);
  wt_kernel<<<dim3(8, 8), dim3(32, 8), 0, stream>>>(Wv, WvT);

  // 3) projections
  gemm_bt<128, 64, 0><<<dim3(4, 128, 1), 256, 0, stream>>>(
      xn, WqT, Qb, BATCH * NTOK, CDIM, CDIM, 0, 0, 0);
  gemm_bt<128, 64, 0><<<dim3(4, 128, 1), 256, 0, stream>>>(
      xn, WkT, Kb, BATCH * NTOK, CDIM, CDIM, 0, 0, 0);
  gemm_bt<128, 64, 1><<<dim3(4, 32, BATCH), 256, 0, stream>>>(
      xn, WvT, VT, NTOK, CDIM, CDIM,
      (size_t)NTOK * CDIM, 0, (size_t)NTOK * CDIM);

  // 4) fused attention + mix + residual + transpose
  fa_kernel<<<dim3(256), 256, 0, stream>>>(Qb, Kb, VT, xn, w1, w2, out);
}

// Round 8
// 337.038 us; speedup vs baseline: 1.1591x; 1.1591x over previous
//
#include <hip/hip_runtime.h>
#include <hip/hip_bf16.h>
#include <cstdint>

typedef unsigned short u16;
typedef __attribute__((ext_vector_type(8))) short bf16x8;
typedef __attribute__((ext_vector_type(4))) float f32x4;

#define BATCH 4
#define CDIM 256
#define NTOK 4096   // H*W

__device__ inline u16 f2bf(float f) {
  union { float f; uint32_t u; } un; un.f = f;
  uint32_t u = un.u;
  u += 0x7fffu + ((u >> 16) & 1u);
  return (u16)(u >> 16);
}
__device__ inline float bf2f(u16 h) {
  union { uint32_t u; float f; } un; un.u = ((uint32_t)h) << 16; return un.f;
}

__device__ inline void gload_lds16(const u16* g, u16* l) {
  __builtin_amdgcn_global_load_lds((const __attribute__((address_space(1))) void*)g,
                                   (__attribute__((address_space(3))) void*)l, 16, 0, 0);
}

// ---------------------------------------------------------------------------
// LayerNorm: x [B, C, N] -> xn bf16 [B*N, C]
// ---------------------------------------------------------------------------
__global__ __launch_bounds__(256) void ln_kernel(const float* __restrict__ x,
                                                 const float* __restrict__ gamma,
                                                 const float* __restrict__ beta,
                                                 u16* __restrict__ xn) {
  __shared__ float tile[CDIM][33];
  __shared__ float reds[8][32];
  __shared__ float reds2[8][32];
  __shared__ float mu_s[32], rs_s[32];

  int b  = blockIdx.x >> 7;
  int n0 = (blockIdx.x & 127) * 32;
  const float* xb = x + (size_t)b * CDIM * NTOK;

  int t = threadIdx.x & 31;
  int g = threadIdx.x >> 5;

  for (int c = g; c < CDIM; c += 8)
    tile[c][t] = xb[(size_t)c * NTOK + n0 + t];
  __syncthreads();

  float s = 0.f, s2 = 0.f;
  for (int c = g * 32; c < g * 32 + 32; ++c) {
    float v = tile[c][t];
    s += v; s2 += v * v;
  }
  reds[g][t] = s; reds2[g][t] = s2;
  __syncthreads();
  if (threadIdx.x < 32) {
    float ts = 0.f, ts2 = 0.f;
    for (int gg = 0; gg < 8; ++gg) { ts += reds[gg][threadIdx.x]; ts2 += reds2[gg][threadIdx.x]; }
    float mu = ts / CDIM;
    float var = ts2 / CDIM - mu * mu;
    mu_s[threadIdx.x] = mu;
    rs_s[threadIdx.x] = rsqrtf(var + 1e-5f);
  }
  __syncthreads();

  int c = threadIdx.x;
  float gam = gamma[c], bet = beta[c];
  u16* out = xn + ((size_t)b * NTOK + n0) * CDIM;
  for (int tt = 0; tt < 32; ++tt) {
    float v = tile[c][tt];
    float y = (v - mu_s[tt]) * rs_s[tt] * gam + bet;
    out[(size_t)tt * CDIM + c] = f2bf(y);
  }
}

// ---------------------------------------------------------------------------
// W [K, Cout] fp32 -> WT bf16 [Cout, K]
// ---------------------------------------------------------------------------
__global__ __launch_bounds__(256) void wt_kernel(const float* __restrict__ W,
                                                 u16* __restrict__ WT) {
  __shared__ float tile[32][33];
  int i0 = blockIdx.y * 32;
  int j0 = blockIdx.x * 32;
  int tx = threadIdx.x, ty = threadIdx.y;
  for (int r = ty; r < 32; r += 8)
    tile[r][tx] = W[(size_t)(i0 + r) * CDIM + j0 + tx];
  __syncthreads();
  for (int r = ty; r < 32; r += 8)
    WT[(size_t)(j0 + r) * CDIM + i0 + tx] = f2bf(tile[tx][r]);
}

// ---------------------------------------------------------------------------
// bf16 MFMA GEMM (projections): C = A[M,K] * B[Nt,K]^T
// MODE 0: bf16 row-major; MODE 1: bf16 transposed C[n*M+m]
// ---------------------------------------------------------------------------
template <int BM, int BN, int MODE>
__global__ __launch_bounds__(256) void gemm_bt(const u16* __restrict__ Ag,
                                               const u16* __restrict__ Bg,
                                               void* __restrict__ Cg,
                                               int M, int Nt, int K,
                                               size_t sA_, size_t sB_, size_t sC_) {
  constexpr int BK = 32;
  constexpr int TM = BM / 32;
  constexpr int TN = BN / 32;
  __shared__ u16 shA[BM][BK + 8];
  __shared__ u16 shB[BN][BK + 8];

  int bz = blockIdx.z;
  const u16* A = Ag + (size_t)bz * sA_;
  const u16* B = Bg + (size_t)bz * sB_;

  int m0 = blockIdx.y * BM;
  int n0 = blockIdx.x * BN;

  int tid  = threadIdx.x;
  int lane = tid & 63;
  int wave = tid >> 6;
  int wm = wave >> 1, wn = wave & 1;
  int col  = lane & 15;
  int quad = lane >> 4;

  f32x4 acc[TM][TN];
#pragma unroll
  for (int i = 0; i < TM; ++i)
#pragma unroll
    for (int j = 0; j < TN; ++j) acc[i][j] = (f32x4){0.f, 0.f, 0.f, 0.f};

  constexpr int ACH = BM * BK / 8;
  constexpr int BCH = BN * BK / 8;

  for (int kb = 0; kb < K; kb += BK) {
    __syncthreads();
#pragma unroll
    for (int c = tid; c < ACH; c += 256) {
      int row = c >> 2, kc = c & 3;
      *(uint4*)&shA[row][kc * 8] = *(const uint4*)&A[(size_t)(m0 + row) * K + kb + kc * 8];
    }
#pragma unroll
    for (int c = tid; c < BCH; c += 256) {
      int row = c >> 2, kc = c & 3;
      *(uint4*)&shB[row][kc * 8] = *(const uint4*)&B[(size_t)(n0 + row) * K + kb + kc * 8];
    }
    __syncthreads();

    bf16x8 af[TM], bfv[TN];
#pragma unroll
    for (int i = 0; i < TM; ++i)
      af[i] = *(const bf16x8*)&shA[wm * (BM / 2) + i * 16 + col][quad * 8];
#pragma unroll
    for (int j = 0; j < TN; ++j)
      bfv[j] = *(const bf16x8*)&shB[wn * (BN / 2) + j * 16 + col][quad * 8];
#pragma unroll
    for (int i = 0; i < TM; ++i)
#pragma unroll
      for (int j = 0; j < TN; ++j)
        acc[i][j] = __builtin_amdgcn_mfma_f32_16x16x32_bf16(af[i], bfv[j], acc[i][j], 0, 0, 0);
  }

  int r0 = quad * 4;
#pragma unroll
  for (int i = 0; i < TM; ++i) {
    int mbase = m0 + wm * (BM / 2) + i * 16 + r0;
#pragma unroll
    for (int j = 0; j < TN; ++j) {
      int n = n0 + wn * (BN / 2) + j * 16 + col;
#pragma unroll
      for (int r = 0; r < 4; ++r) {
        int m = mbase + r;
        float v = acc[i][j][r];
        if (MODE == 0) {
          ((u16*)Cg)[(size_t)bz * sC_ + (size_t)m * Nt + n] = f2bf(v);
        } else {
          ((u16*)Cg)[(size_t)bz * sC_ + (size_t)n * M + m] = f2bf(v);
        }
      }
    }
  }
}

// ---------------------------------------------------------------------------
// Fused attention, TWO-PASS exact softmax + C-split for occupancy.
// Block = 256 thr = 4 waves: wave = g*2+h, g = row-group (16 Q rows of a
// 32-row Q tile), h = C-half (128 of 256 output channels).
// Pass 1 (64 iters, K-tile 64): per-lane online (m,l); merged once at end.
// Pass 2 (128 iters, K-tile 32 + V-tile 32): S recomputed per C-half wave,
// P = a1*exp(S-m)/l + a2*relu^2 as ONE combined bf16 matrix, single O
// accumulator, one barrier per iter.
// ~150 regs/wave, ~70 KB LDS -> 2 blocks/CU -> 2 waves/SIMD.
// NOTE: no arrays of LDS pointers (addrspacecast static-init bug) — rotate
// scalar pointers / select with ternary instead.
// ---------------------------------------------------------------------------
__global__ __launch_bounds__(256, 2) void fa_kernel(const u16* __restrict__ Qg,
                                                    const u16* __restrict__ Kg,
                                                    const u16* __restrict__ Vtg,
                                                    const u16* __restrict__ xng,
                                                    const float* __restrict__ w1p,
                                                    const float* __restrict__ w2p,
                                                    float* __restrict__ outg) {
  // A 32768 | B 32768 | P 5120 | stats 512  = 71168 B
  __shared__ __align__(16) char smem[71168];
  float* otile = (float*)smem;          // epilogue overlay [256][36] f32

  int b  = blockIdx.x & 3;              // XCD swizzle: same XCD -> same batch
  int q0 = (blockIdx.x >> 2) * 32;

  const u16* Q  = Qg  + (size_t)b * NTOK * CDIM;
  const u16* K  = Kg  + (size_t)b * NTOK * CDIM;
  const u16* Vt = Vtg + (size_t)b * NTOK * CDIM;

  int tid  = threadIdx.x;
  int lane = tid & 63;
  int wave = tid >> 6;
  int g = wave >> 1, h = wave & 1;
  int col = lane & 15, quad = lane >> 4;

  u16* P = (u16*)(smem + 65536) + wave * 640;   // private [16][40] u16

  float e1 = __expf(w1p[0]), e2 = __expf(w2p[0]);
  float a1 = e1 / (e1 + e2), a2 = e2 / (e1 + e2);

  // ---- Q A-frags from global (16B contiguous per frag), live both passes --
  bf16x8 aq[8];
#pragma unroll
  for (int kk = 0; kk < 8; ++kk)
    aq[kk] = *(const bf16x8*)&Q[(size_t)(q0 + g * 16 + col) * CDIM + kk * 32 + quad * 8];

  // =========================== PASS 1: m, l ================================
  u16* ka = (u16*)smem;            // K tile 64: [64][256] u16 = 32 KB
  u16* kb = ka + 16384;

  auto stage1 = [&](int n1, u16* Kdst) {
#pragma unroll
    for (int it = 0; it < 8; ++it) {
      int c = it * 256 + wave * 64 + lane;
      int row = c >> 5, pos = c & 31;
      int ch = pos ^ (row & 31);      // masked on BOTH stage and read sides
      gload_lds16(K + (size_t)(n1 + row) * CDIM + ch * 8,
                  Kdst + (size_t)(it * 256 + wave * 64) * 8);
    }
  };

  stage1(0, ka);

  float ml[4], ll[4];
#pragma unroll
  for (int r = 0; r < 4; ++r) { ml[r] = -3e38f; ll[r] = 0.f; }

  __syncthreads();

  for (int t = 0; t < 64; ++t) {
    if (t < 63) stage1((t + 1) * 64, kb);

    f32x4 s[2];
#pragma unroll
    for (int j = 0; j < 2; ++j) s[j] = (f32x4){0.f, 0.f, 0.f, 0.f};
#pragma unroll
    for (int kk = 0; kk < 8; ++kk) {
#pragma unroll
      for (int j = 0; j < 2; ++j) {
        int kr = h * 32 + j * 16 + col;
        bf16x8 bk = *(const bf16x8*)&ka[(size_t)kr * 256 + (((kk * 4 + quad) ^ kr) & 31) * 8];
        s[j] = __builtin_amdgcn_mfma_f32_16x16x32_bf16(aq[kk], bk, s[j], 0, 0, 0);
      }
    }
    // per-lane online update; NO cross-lane traffic in the loop
#pragma unroll
    for (int r = 0; r < 4; ++r) {
      float pm = fmaxf(s[0][r], s[1][r]);
      float mn = fmaxf(ml[r], pm);
      ll[r] = ll[r] * __expf(ml[r] - mn) + __expf(s[0][r] - mn) + __expf(s[1][r] - mn);
      ml[r] = mn;
    }
    __syncthreads();
    u16* tk = ka; ka = kb; kb = tk;
  }

  // merge across the 16 cols of this wave (4 shuffle steps, once)
#pragma unroll
  for (int off = 1; off < 16; off <<= 1)
#pragma unroll
    for (int r = 0; r < 4; ++r) {
      float mo = __shfl_xor(ml[r], off);
      float lo = __shfl_xor(ll[r], off);
      float mn = fmaxf(ml[r], mo);
      ll[r] = ll[r] * __expf(ml[r] - mn) + lo * __expf(mo - mn);
      ml[r] = mn;
    }
  // merge the two key-halves (h waves of this group) via LDS, once
  float* mbuf = (float*)(smem + 70656);   // [2g][2h][16]
  float* lbuf = mbuf + 64;
  if (col == 0) {
#pragma unroll
    for (int r = 0; r < 4; ++r) {
      mbuf[(g * 2 + h) * 16 + quad * 4 + r] = ml[r];
      lbuf[(g * 2 + h) * 16 + quad * 4 + r] = ll[r];
    }
  }
  __syncthreads();
  float mf[4], c1[4];
#pragma unroll
  for (int r = 0; r < 4; ++r) {
    float mo = mbuf[(g * 2 + (1 - h)) * 16 + quad * 4 + r];
    float lo = lbuf[(g * 2 + (1 - h)) * 16 + quad * 4 + r];
    float mn = fmaxf(ml[r], mo);
    float lf = ll[r] * __expf(ml[r] - mn) + lo * __expf(mo - mn);
    mf[r] = mn;
    c1[r] = a1 / lf;
  }

  // =========================== PASS 2: P, O ================================
  u16* k2a = (u16*)smem;                 // [32][256] u16 = 16 KB
  u16* k2b = k2a + 8192;
  u16* v2a = (u16*)(smem + 32768);       // [256][32] u16 = 16 KB
  u16* v2b = v2a + 8192;

  auto stage2 = [&](int n1, u16* Kdst, u16* Vdst) {
#pragma unroll
    for (int it = 0; it < 4; ++it) {
      int c = it * 256 + wave * 64 + lane;
      int row = c >> 5, pos = c & 31;
      int ch = pos ^ row;
      gload_lds16(K + (size_t)(n1 + row) * CDIM + ch * 8,
                  Kdst + (size_t)(it * 256 + wave * 64) * 8);
    }
#pragma unroll
    for (int it = 0; it < 4; ++it) {
      int c = it * 256 + wave * 64 + lane;
      int row = c >> 2, pos = c & 3;
      int ch = pos ^ ((row >> 1) & 3);
      gload_lds16(Vt + (size_t)row * NTOK + n1 + ch * 8,
                  Vdst + (size_t)(it * 256 + wave * 64) * 8);
    }
  };

  f32x4 o[8];
#pragma unroll
  for (int j = 0; j < 8; ++j) o[j] = (f32x4){0.f, 0.f, 0.f, 0.f};

  stage2(0, k2a, v2a);
  __syncthreads();

  for (int t = 0; t < 128; ++t) {
    if (t < 127) stage2((t + 1) * 32, ((t + 1) & 1) ? k2b : k2a,
                        ((t + 1) & 1) ? v2b : v2a);
    const u16* ks = (t & 1) ? k2b : k2a;
    const u16* vs = (t & 1) ? v2b : v2a;

    // S (redundant per C-half wave; avoids cross-wave P handoff)
    f32x4 s[2];
#pragma unroll
    for (int j = 0; j < 2; ++j) s[j] = (f32x4){0.f, 0.f, 0.f, 0.f};
#pragma unroll
    for (int kk = 0; kk < 8; ++kk) {
#pragma unroll
      for (int j = 0; j < 2; ++j) {
        int kr = j * 16 + col;
        bf16x8 bk = *(const bf16x8*)&ks[(size_t)kr * 256 + (((kk * 4 + quad) ^ kr) & 31) * 8];
        s[j] = __builtin_amdgcn_mfma_f32_16x16x32_bf16(aq[kk], bk, s[j], 0, 0, 0);
      }
    }

    // combined P = a1*exp(S-m)/l + a2*relu(S)^2  (no reductions, no rescale)
#pragma unroll
    for (int j = 0; j < 2; ++j)
#pragma unroll
      for (int r = 0; r < 4; ++r) {
        float sv = s[j][r];
        float rl = sv > 0.f ? sv * sv : 0.f;
        float p = c1[r] * __expf(sv - mf[r]) + a2 * rl;
        P[(size_t)(quad * 4 + r) * 40 + j * 16 + col] = f2bf(p);
      }

    // PV over this wave's 128 channels (single accumulator)
    bf16x8 pa = *(const bf16x8*)&P[(size_t)col * 40 + quad * 8];
#pragma unroll
    for (int j = 0; j < 8; ++j) {
      int vr = h * 128 + j * 16 + col;
      bf16x8 bv = *(const bf16x8*)&vs[(size_t)vr * 32 + (quad ^ ((vr >> 1) & 3)) * 8];
      o[j] = __builtin_amdgcn_mfma_f32_16x16x32_bf16(pa, bv, o[j], 0, 0, 0);
    }

    __syncthreads();   // prefetch landed + all waves done with current bufs
  }

  // ---- epilogue: residual + transpose to [c][n] ----
#pragma unroll
  for (int j = 0; j < 8; ++j) {
    int c = h * 128 + j * 16 + col;
    float4 v4;
    float* vv = (float*)&v4;
#pragma unroll
    for (int r = 0; r < 4; ++r) {
      int row = g * 16 + quad * 4 + r;
      vv[r] = o[j][r] + bf2f(xng[((size_t)b * NTOK + q0 + row) * CDIM + c]);
    }
    *(float4*)&otile[(size_t)c * 36 + g * 16 + quad * 4] = v4;
  }
  __syncthreads();

#pragma unroll
  for (int it = 0; it < 8; ++it) {
    int c  = it * 32 + (tid >> 3);
    int ch = tid & 7;
    *(float4*)&outg[((size_t)b * CDIM + c) * NTOK + q0 + ch * 4] =
        *(const float4*)&otile[(size_t)c * 36 + ch * 4];
  }
}

// ---------------------------------------------------------------------------
extern "C" void kernel_launch(void* const* d_in, const int* in_sizes, int n_in,
                              void* d_out, int out_size, void* d_ws, size_t ws_size,
                              hipStream_t stream) {
  const float* x     = (const float*)d_in[0];
  const float* gamma = (const float*)d_in[1];
  const float* beta  = (const float*)d_in[2];
  const float* Wq    = (const float*)d_in[3];
  const float* Wk    = (const float*)d_in[4];
  const float* Wv    = (const float*)d_in[5];
  const float* w1    = (const float*)d_in[6];
  const float* w2    = (const float*)d_in[7];
  float* out = (float*)d_out;

  char* ws = (char*)d_ws;
  size_t off = 0;
  u16* xn  = (u16*)(ws + off); off += (size_t)BATCH * NTOK * CDIM * 2;
  u16* WqT = (u16*)(ws + off); off += (size_t)CDIM * CDIM * 2;
  u16* WkT = (u16*)(ws + off); off += (size_t)CDIM * CDIM * 2;
  u16* WvT = (u16*)(ws + off); off += (size_t)CDIM * CDIM * 2;
  u16* Qb  = (u16*)(ws + off); off += (size_t)BATCH * NTOK * CDIM * 2;
  u16* Kb  = (u16*)(ws + off); off += (size_t)BATCH * NTOK * CDIM * 2;
  u16* VT  = (u16*)(ws + off); off += (size_t)BATCH * NTOK * CDIM * 2;  // [b][c][n]

  // 1) LayerNorm -> xn bf16 [B*N, C]
  ln_kernel<<<dim3(BATCH * (NTOK / 32)), 256, 0, stream>>>(x, gamma, beta, xn);

  // 2) weight transposes
  wt_kernel<<<dim3(8, 8), dim3(32, 8), 0, stream>>>(Wq, WqT);
  wt_kernel<<<dim3(8, 8), dim3(32, 8), 0, stream>>>(Wk, WkT);
  wt_kernel<<<dim3(8, 8), dim3(32, 8), 0, stream>>>(Wv, WvT);

  // 3) projections
  gemm_bt<128, 64, 0><<<dim3(4, 128, 1), 256, 0, stream>>>(
      xn, WqT, Qb, BATCH * NTOK, CDIM, CDIM, 0, 0, 0);
  gemm_bt<128, 64, 0><<<dim3(4, 128, 1), 256, 0, stream>>>(
      xn, WkT, Kb, BATCH * NTOK, CDIM, CDIM, 0, 0, 0);
  gemm_bt<128, 64, 1><<<dim3(4, 32, BATCH), 256, 0, stream>>>(
      xn, WvT, VT, NTOK, CDIM, CDIM,
      (size_t)NTOK * CDIM, 0, (size_t)NTOK * CDIM);

  // 4) fused attention (two-pass) + mix + residual + transpose
  fa_kernel<<<dim3(512), 256, 0, stream>>>(Qb, Kb, VT, xn, w1, w2, out);
}

// Round 10
// 329.723 us; speedup vs baseline: 1.1848x; 1.0222x over previous
//
#include <hip/hip_runtime.h>
#include <hip/hip_bf16.h>
#include <cstdint>

typedef unsigned short u16;
typedef __attribute__((ext_vector_type(8))) short bf16x8;
typedef __attribute__((ext_vector_type(4))) float f32x4;

#define BATCH 4
#define CDIM 256
#define NTOK 4096   // H*W

__device__ inline float fexp2(float x) { return __builtin_amdgcn_exp2f(x); }

__device__ inline u16 f2bf(float f) {
  union { float f; uint32_t u; } un; un.f = f;
  uint32_t u = un.u;
  u += 0x7fffu + ((u >> 16) & 1u);
  return (u16)(u >> 16);
}
__device__ inline float bf2f(u16 h) {
  union { uint32_t u; float f; } un; un.u = ((uint32_t)h) << 16; return un.f;
}

__device__ inline void gload_lds16(const u16* g, u16* l) {
  __builtin_amdgcn_global_load_lds((const __attribute__((address_space(1))) void*)g,
                                   (__attribute__((address_space(3))) void*)l, 16, 0, 0);
}

// ---------------------------------------------------------------------------
// LayerNorm: x [B, C, N] -> xn bf16 [B*N, C]
// ---------------------------------------------------------------------------
__global__ __launch_bounds__(256) void ln_kernel(const float* __restrict__ x,
                                                 const float* __restrict__ gamma,
                                                 const float* __restrict__ beta,
                                                 u16* __restrict__ xn) {
  __shared__ float tile[CDIM][33];
  __shared__ float reds[8][32];
  __shared__ float reds2[8][32];
  __shared__ float mu_s[32], rs_s[32];

  int b  = blockIdx.x >> 7;
  int n0 = (blockIdx.x & 127) * 32;
  const float* xb = x + (size_t)b * CDIM * NTOK;

  int t = threadIdx.x & 31;
  int g = threadIdx.x >> 5;

  for (int c = g; c < CDIM; c += 8)
    tile[c][t] = xb[(size_t)c * NTOK + n0 + t];
  __syncthreads();

  float s = 0.f, s2 = 0.f;
  for (int c = g * 32; c < g * 32 + 32; ++c) {
    float v = tile[c][t];
    s += v; s2 += v * v;
  }
  reds[g][t] = s; reds2[g][t] = s2;
  __syncthreads();
  if (threadIdx.x < 32) {
    float ts = 0.f, ts2 = 0.f;
    for (int gg = 0; gg < 8; ++gg) { ts += reds[gg][threadIdx.x]; ts2 += reds2[gg][threadIdx.x]; }
    float mu = ts / CDIM;
    float var = ts2 / CDIM - mu * mu;
    mu_s[threadIdx.x] = mu;
    rs_s[threadIdx.x] = rsqrtf(var + 1e-5f);
  }
  __syncthreads();

  int c = threadIdx.x;
  float gam = gamma[c], bet = beta[c];
  u16* out = xn + ((size_t)b * NTOK + n0) * CDIM;
  for (int tt = 0; tt < 32; ++tt) {
    float v = tile[c][tt];
    float y = (v - mu_s[tt]) * rs_s[tt] * gam + bet;
    out[(size_t)tt * CDIM + c] = f2bf(y);
  }
}

// ---------------------------------------------------------------------------
// W [K, Cout] fp32 -> WT bf16 [Cout, K], optional scale (log2e for Wq)
// ---------------------------------------------------------------------------
__global__ __launch_bounds__(256) void wt_kernel(const float* __restrict__ W,
                                                 u16* __restrict__ WT,
                                                 float scale) {
  __shared__ float tile[32][33];
  int i0 = blockIdx.y * 32;
  int j0 = blockIdx.x * 32;
  int tx = threadIdx.x, ty = threadIdx.y;
  for (int r = ty; r < 32; r += 8)
    tile[r][tx] = W[(size_t)(i0 + r) * CDIM + j0 + tx];
  __syncthreads();
  for (int r = ty; r < 32; r += 8)
    WT[(size_t)(j0 + r) * CDIM + i0 + tx] = f2bf(tile[tx][r] * scale);
}

// ---------------------------------------------------------------------------
// Fused QKV projection: A = xn [16384,256], B3 = stacked [WqT;WkT;WvT]
// [768,256]. One block = 128 m x 64 n; n-range selects output:
//   n<256 -> Qb row-major | n<512 -> Kb row-major | else -> VT transposed.
// ---------------------------------------------------------------------------
__global__ __launch_bounds__(256) void qkv_kernel(const u16* __restrict__ A,
                                                  const u16* __restrict__ B3,
                                                  u16* __restrict__ Qb,
                                                  u16* __restrict__ Kb,
                                                  u16* __restrict__ VT) {
  constexpr int BM = 128, BN = 64, BK = 32;
  __shared__ u16 shA[BM][BK + 8];
  __shared__ u16 shB[BN][BK + 8];

  int m0 = blockIdx.y * BM;
  int n0 = blockIdx.x * BN;

  int tid  = threadIdx.x;
  int lane = tid & 63;
  int wave = tid >> 6;
  int wm = wave >> 1, wn = wave & 1;
  int col  = lane & 15;
  int quad = lane >> 4;

  f32x4 acc[4][2];
#pragma unroll
  for (int i = 0; i < 4; ++i)
#pragma unroll
    for (int j = 0; j < 2; ++j) acc[i][j] = (f32x4){0.f, 0.f, 0.f, 0.f};

  for (int kb = 0; kb < CDIM; kb += BK) {
    __syncthreads();
#pragma unroll
    for (int c = tid; c < BM * BK / 8; c += 256) {
      int row = c >> 2, kc = c & 3;
      *(uint4*)&shA[row][kc * 8] = *(const uint4*)&A[(size_t)(m0 + row) * CDIM + kb + kc * 8];
    }
#pragma unroll
    for (int c = tid; c < BN * BK / 8; c += 256) {
      int row = c >> 2, kc = c & 3;
      *(uint4*)&shB[row][kc * 8] = *(const uint4*)&B3[(size_t)(n0 + row) * CDIM + kb + kc * 8];
    }
    __syncthreads();

    bf16x8 af[4], bfv[2];
#pragma unroll
    for (int i = 0; i < 4; ++i)
      af[i] = *(const bf16x8*)&shA[wm * 64 + i * 16 + col][quad * 8];
#pragma unroll
    for (int j = 0; j < 2; ++j)
      bfv[j] = *(const bf16x8*)&shB[wn * 32 + j * 16 + col][quad * 8];
#pragma unroll
    for (int i = 0; i < 4; ++i)
#pragma unroll
      for (int j = 0; j < 2; ++j)
        acc[i][j] = __builtin_amdgcn_mfma_f32_16x16x32_bf16(af[i], bfv[j], acc[i][j], 0, 0, 0);
  }

  int mode = n0 >> 8;   // 0:Q 1:K 2:V (block-uniform)
  int r0 = quad * 4;
#pragma unroll
  for (int i = 0; i < 4; ++i) {
    int mbase = m0 + wm * 64 + i * 16 + r0;
#pragma unroll
    for (int j = 0; j < 2; ++j) {
      int n = n0 + wn * 32 + j * 16 + col;
#pragma unroll
      for (int r = 0; r < 4; ++r) {
        int m = mbase + r;
        float v = acc[i][j][r];
        if (mode == 0) {
          Qb[(size_t)m * CDIM + n] = f2bf(v);
        } else if (mode == 1) {
          Kb[(size_t)m * CDIM + (n - 256)] = f2bf(v);
        } else {
          int cv = n - 512, bb = m >> 12, nt = m & 4095;
          VT[((size_t)bb * CDIM + cv) * NTOK + nt] = f2bf(v);
        }
      }
    }
  }
}

// ---------------------------------------------------------------------------
// Fused attention, TWO-PASS exact softmax + C-split (R8 structure) with:
//  - exp2 domain (Q pre-scaled by log2e; relu^2 corrected by ln2^2)
//  - hoisted staging addresses (per-thread swizzled offsets precomputed)
//  - pass-1 lazy rescale (__any skip when no row max moved)
// ---------------------------------------------------------------------------
__global__ __launch_bounds__(256, 2) void fa_kernel(const u16* __restrict__ Qg,
                                                    const u16* __restrict__ Kg,
                                                    const u16* __restrict__ Vtg,
                                                    const u16* __restrict__ xng,
                                                    const float* __restrict__ w1p,
                                                    const float* __restrict__ w2p,
                                                    float* __restrict__ outg) {
  // A 32768 | B 32768 | P 5120 | stats 512  = 71168 B
  __shared__ __align__(16) char smem[71168];
  float* otile = (float*)smem;          // epilogue overlay [256][36] f32

  int b  = blockIdx.x & 3;              // XCD swizzle: same XCD -> same batch
  int q0 = (blockIdx.x >> 2) * 32;

  const u16* Q  = Qg  + (size_t)b * NTOK * CDIM;
  const u16* K  = Kg  + (size_t)b * NTOK * CDIM;
  const u16* Vt = Vtg + (size_t)b * NTOK * CDIM;

  int tid  = threadIdx.x;
  int lane = tid & 63;
  int wave = tid >> 6;
  int g = wave >> 1, h = wave & 1;
  int col = lane & 15, quad = lane >> 4;

  u16* P = (u16*)(smem + 65536) + wave * 640;   // private [16][40] u16

  float e1 = __expf(w1p[0]), e2 = __expf(w2p[0]);
  float a1 = e1 / (e1 + e2), a2 = e2 / (e1 + e2);
  float a2p = a2 * 0.4804530139182014f;   // a2 * ln2^2 (S is in log2e domain)

  // ---- Q A-frags from global (16B contiguous per frag), live both passes --
  bf16x8 aq[8];
#pragma unroll
  for (int kk = 0; kk < 8; ++kk)
    aq[kk] = *(const bf16x8*)&Q[(size_t)(q0 + g * 16 + col) * CDIM + kk * 32 + quad * 8];

  // ---- precomputed per-thread staging offsets (u16 elements) ----
  int koff1[8];
#pragma unroll
  for (int it = 0; it < 8; ++it) {
    int row = it * 8 + (tid >> 5);
    int ch  = (tid & 31) ^ (row & 31);
    koff1[it] = row * CDIM + ch * 8;
  }
  int koff2[4], voff2[4];
#pragma unroll
  for (int it = 0; it < 4; ++it) {
    int row = it * 8 + (tid >> 5);
    int ch  = (tid & 31) ^ row;           // row < 32
    koff2[it] = row * CDIM + ch * 8;
    int vr  = it * 64 + (tid >> 2);
    int vch = (tid & 3) ^ ((vr >> 1) & 3);
    voff2[it] = vr * NTOK + vch * 8;
  }

  // =========================== PASS 1: m, l ================================
  u16* ka = (u16*)smem;            // K tile 64: [64][256] u16 = 32 KB
  u16* kb = ka + 16384;

  auto stage1 = [&](int n1, u16* Kdst) {
    const u16* kgb = K + (size_t)n1 * CDIM;
#pragma unroll
    for (int it = 0; it < 8; ++it)
      gload_lds16(kgb + koff1[it], Kdst + (size_t)(it * 256 + wave * 64) * 8);
  };

  stage1(0, ka);

  float ml[4], ll[4];
#pragma unroll
  for (int r = 0; r < 4; ++r) { ml[r] = -3e38f; ll[r] = 0.f; }

  __syncthreads();

  for (int t = 0; t < 64; ++t) {
    if (t < 63) stage1((t + 1) * 64, kb);

    f32x4 s[2];
#pragma unroll
    for (int j = 0; j < 2; ++j) s[j] = (f32x4){0.f, 0.f, 0.f, 0.f};
#pragma unroll
    for (int kk = 0; kk < 8; ++kk) {
#pragma unroll
      for (int j = 0; j < 2; ++j) {
        int kr = h * 32 + j * 16 + col;
        bf16x8 bk = *(const bf16x8*)&ka[(size_t)kr * 256 + (((kk * 4 + quad) ^ kr) & 31) * 8];
        s[j] = __builtin_amdgcn_mfma_f32_16x16x32_bf16(aq[kk], bk, s[j], 0, 0, 0);
      }
    }
    // per-lane online update (exp2 domain); lazy rescale when max stable
    float mnew[4];
    bool chg = false;
#pragma unroll
    for (int r = 0; r < 4; ++r) {
      float pm = fmaxf(s[0][r], s[1][r]);
      mnew[r] = fmaxf(ml[r], pm);
      chg = chg || (mnew[r] > ml[r]);
    }
    if (__any(chg)) {
#pragma unroll
      for (int r = 0; r < 4; ++r) {
        ll[r] = ll[r] * fexp2(ml[r] - mnew[r]) +
                fexp2(s[0][r] - mnew[r]) + fexp2(s[1][r] - mnew[r]);
        ml[r] = mnew[r];
      }
    } else {
#pragma unroll
      for (int r = 0; r < 4; ++r)
        ll[r] += fexp2(s[0][r] - ml[r]) + fexp2(s[1][r] - ml[r]);
    }
    __syncthreads();
    u16* tk = ka; ka = kb; kb = tk;
  }

  // merge across the 16 cols of this wave (4 shuffle steps, once)
#pragma unroll
  for (int off = 1; off < 16; off <<= 1)
#pragma unroll
    for (int r = 0; r < 4; ++r) {
      float mo = __shfl_xor(ml[r], off);
      float lo = __shfl_xor(ll[r], off);
      float mn = fmaxf(ml[r], mo);
      ll[r] = ll[r] * fexp2(ml[r] - mn) + lo * fexp2(mo - mn);
      ml[r] = mn;
    }
  // merge the two key-halves (h waves of this group) via LDS, once
  float* mbuf = (float*)(smem + 70656);   // [2g][2h][16]
  float* lbuf = mbuf + 64;
  if (col == 0) {
#pragma unroll
    for (int r = 0; r < 4; ++r) {
      mbuf[(g * 2 + h) * 16 + quad * 4 + r] = ml[r];
      lbuf[(g * 2 + h) * 16 + quad * 4 + r] = ll[r];
    }
  }
  __syncthreads();
  float mf[4], c1[4];
#pragma unroll
  for (int r = 0; r < 4; ++r) {
    float mo = mbuf[(g * 2 + (1 - h)) * 16 + quad * 4 + r];
    float lo = lbuf[(g * 2 + (1 - h)) * 16 + quad * 4 + r];
    float mn = fmaxf(ml[r], mo);
    float lf = ll[r] * fexp2(ml[r] - mn) + lo * fexp2(mo - mn);
    mf[r] = mn;
    c1[r] = a1 / lf;
  }

  // =========================== PASS 2: P, O ================================
  u16* k2a = (u16*)smem;                 // [32][256] u16 = 16 KB
  u16* k2b = k2a + 8192;
  u16* v2a = (u16*)(smem + 32768);       // [256][32] u16 = 16 KB
  u16* v2b = v2a + 8192;

  auto stage2 = [&](int n1, u16* Kdst, u16* Vdst) {
    const u16* kgb = K + (size_t)n1 * CDIM;
    const u16* vgb = Vt + n1;
#pragma unroll
    for (int it = 0; it < 4; ++it)
      gload_lds16(kgb + koff2[it], Kdst + (size_t)(it * 256 + wave * 64) * 8);
#pragma unroll
    for (int it = 0; it < 4; ++it)
      gload_lds16(vgb + voff2[it], Vdst + (size_t)(it * 256 + wave * 64) * 8);
  };

  f32x4 o[8];
#pragma unroll
  for (int j = 0; j < 8; ++j) o[j] = (f32x4){0.f, 0.f, 0.f, 0.f};

  stage2(0, k2a, v2a);
  __syncthreads();

  for (int t = 0; t < 128; ++t) {
    if (t < 127) stage2((t + 1) * 32, ((t + 1) & 1) ? k2b : k2a,
                        ((t + 1) & 1) ? v2b : v2a);
    const u16* ks = (t & 1) ? k2b : k2a;
    const u16* vs = (t & 1) ? v2b : v2a;

    // S (redundant per C-half wave; avoids cross-wave P handoff)
    f32x4 s[2];
#pragma unroll
    for (int j = 0; j < 2; ++j) s[j] = (f32x4){0.f, 0.f, 0.f, 0.f};
#pragma unroll
    for (int kk = 0; kk < 8; ++kk) {
#pragma unroll
      for (int j = 0; j < 2; ++j) {
        int kr = j * 16 + col;
        bf16x8 bk = *(const bf16x8*)&ks[(size_t)kr * 256 + (((kk * 4 + quad) ^ kr) & 31) * 8];
        s[j] = __builtin_amdgcn_mfma_f32_16x16x32_bf16(aq[kk], bk, s[j], 0, 0, 0);
      }
    }

    // combined P = c1*exp2(S-m) + a2p*relu(S)^2  (no reductions, no rescale)
#pragma unroll
    for (int j = 0; j < 2; ++j)
#pragma unroll
      for (int r = 0; r < 4; ++r) {
        float sv = s[j][r];
        float rl = sv > 0.f ? sv * sv : 0.f;
        float p = c1[r] * fexp2(sv - mf[r]) + a2p * rl;
        P[(size_t)(quad * 4 + r) * 40 + j * 16 + col] = f2bf(p);
      }

    // PV over this wave's 128 channels (single accumulator)
    bf16x8 pa = *(const bf16x8*)&P[(size_t)col * 40 + quad * 8];
#pragma unroll
    for (int j = 0; j < 8; ++j) {
      int vr = h * 128 + j * 16 + col;
      bf16x8 bv = *(const bf16x8*)&vs[(size_t)vr * 32 + (quad ^ ((vr >> 1) & 3)) * 8];
      o[j] = __builtin_amdgcn_mfma_f32_16x16x32_bf16(pa, bv, o[j], 0, 0, 0);
    }

    __syncthreads();   // prefetch landed + all waves done with current bufs
  }

  // ---- epilogue: residual + transpose to [c][n] ----
#pragma unroll
  for (int j = 0; j < 8; ++j) {
    int c = h * 128 + j * 16 + col;
    float4 v4;
    float* vv = (float*)&v4;
#pragma unroll
    for (int r = 0; r < 4; ++r) {
      int row = g * 16 + quad * 4 + r;
      vv[r] = o[j][r] + bf2f(xng[((size_t)b * NTOK + q0 + row) * CDIM + c]);
    }
    *(float4*)&otile[(size_t)c * 36 + g * 16 + quad * 4] = v4;
  }
  __syncthreads();

#pragma unroll
  for (int it = 0; it < 8; ++it) {
    int c  = it * 32 + (tid >> 3);
    int ch = tid & 7;
    *(float4*)&outg[((size_t)b * CDIM + c) * NTOK + q0 + ch * 4] =
        *(const float4*)&otile[(size_t)c * 36 + ch * 4];
  }
}

// ---------------------------------------------------------------------------
extern "C" void kernel_launch(void* const* d_in, const int* in_sizes, int n_in,
                              void* d_out, int out_size, void* d_ws, size_t ws_size,
                              hipStream_t stream) {
  const float* x     = (const float*)d_in[0];
  const float* gamma = (const float*)d_in[1];
  const float* beta  = (const float*)d_in[2];
  const float* Wq    = (const float*)d_in[3];
  const float* Wk    = (const float*)d_in[4];
  const float* Wv    = (const float*)d_in[5];
  const float* w1    = (const float*)d_in[6];
  const float* w2    = (const float*)d_in[7];
  float* out = (float*)d_out;

  char* ws = (char*)d_ws;
  size_t off = 0;
  u16* xn  = (u16*)(ws + off); off += (size_t)BATCH * NTOK * CDIM * 2;
  u16* WT3 = (u16*)(ws + off); off += (size_t)3 * CDIM * CDIM * 2;   // [768][256]
  u16* Qb  = (u16*)(ws + off); off += (size_t)BATCH * NTOK * CDIM * 2;
  u16* Kb  = (u16*)(ws + off); off += (size_t)BATCH * NTOK * CDIM * 2;
  u16* VT  = (u16*)(ws + off); off += (size_t)BATCH * NTOK * CDIM * 2;  // [b][c][n]

  const float LOG2E = 1.4426950408889634f;

  // 1) LayerNorm -> xn bf16 [B*N, C]
  ln_kernel<<<dim3(BATCH * (NTOK / 32)), 256, 0, stream>>>(x, gamma, beta, xn);

  // 2) stacked transposed weights (Wq pre-scaled by log2e -> exp2-domain S)
  wt_kernel<<<dim3(8, 8), dim3(32, 8), 0, stream>>>(Wq, WT3, LOG2E);
  wt_kernel<<<dim3(8, 8), dim3(32, 8), 0, stream>>>(Wk, WT3 + 256 * 256, 1.0f);
  wt_kernel<<<dim3(8, 8), dim3(32, 8), 0, stream>>>(Wv, WT3 + 512 * 256, 1.0f);

  // 3) fused Q/K/V projection (one launch)
  qkv_kernel<<<dim3(12, 128), 256, 0, stream>>>(xn, WT3, Qb, Kb, VT);

  // 4) fused attention (two-pass) + mix + residual + transpose
  fa_kernel<<<dim3(512), 256, 0, stream>>>(Qb, Kb, VT, xn, w1, w2, out);
}